// Round 3
// baseline (127.307 us; speedup 1.0000x reference)
//
#include <hip/hip_runtime.h>
#include <math.h>

#define KBINS 16
#define HID 16
// ln(0.02)
#define LN_SIGMA1 (-3.912023005428146f)

typedef __attribute__((ext_vector_type(4))) float f32x4;

// Force a wave-uniform value into an SGPR (weights are uniform per block).
__device__ __forceinline__ float to_sgpr(float x) {
    return __int_as_float(__builtin_amdgcn_readfirstlane(__float_as_int(x)));
}

// Phi(x) = 0.5*(1+erf(x)) via A&S 7.1.27 (|err| <= 5e-4), branchless,
// saturates to 0/1 at large |x| through q^4 -> inf, rcp(inf) = 0.
__device__ __forceinline__ float phi_fast(float x) {
    float ax = fabsf(x);
    float p  = fmaf(0.078108f, ax, 0.000972f);
    p        = fmaf(p, ax, 0.230389f);
    p        = fmaf(p, ax, 0.278393f);
    float q  = fmaf(p, ax, 1.0f);
    float q2 = q * q;
    float hr = 0.5f * __builtin_amdgcn_rcpf(q2 * q2);
    return (x >= 0.0f) ? (1.0f - hr) : hr;
}

__global__ __launch_bounds__(256, 6) void bfn_kernel(
    const float* __restrict__ mu,
    const float* __restrict__ t,
    const float* __restrict__ W1,   // [2,16]
    const float* __restrict__ b1,   // [16]
    const float* __restrict__ W2,   // [16,2]
    const float* __restrict__ b2,   // [2]
    float* __restrict__ out,        // [B,D,16]
    int D)
{
    const int b    = blockIdx.y;
    const int tid  = threadIdx.x;
    const int lane = tid & 63;
    const int d0   = blockIdx.x * 256;
    const int d    = d0 + tid;

    // ---- wave-uniform per-row constants ----
    const float tb    = t[b];
    const float gamma = -expm1f(2.0f * tb * LN_SIGMA1);  // 1 - 0.02^(2t)
    const float inv_gamma = 1.0f / gamma;
    const float var_scale = sqrtf((1.0f - gamma) * inv_gamma);
    const bool  tiny_t = (tb < 1e-6f);

    // weights -> SGPRs (uniform); c1 = t*W1[1]+b1 stays VGPR
    float w1a[HID], c1[HID], w20[HID], w21[HID];
#pragma unroll
    for (int i = 0; i < HID; ++i) {
        w1a[i] = to_sgpr(W1[i]);
        c1[i]  = fmaf(tb, W1[HID + i], b1[i]);
        w20[i] = to_sgpr(W2[2 * i]);
        w21[i] = to_sgpr(W2[2 * i + 1]);
    }

    const bool full = (d0 + 256 <= D);   // D=49152 -> always true
    const float m = (full || d < D) ? mu[(size_t)b * D + d] : 0.0f;

    // ---- MLP: gelu(tanh approx) == pre * sigmoid(2u) ----
    float o0 = to_sgpr(b2[0]);
    float o1 = to_sgpr(b2[1]);
#pragma unroll
    for (int i = 0; i < HID; ++i) {
        float pre = fmaf(m, w1a[i], c1[i]);
        float p2  = pre * pre;
        float z   = pre * fmaf(p2, -0.0713552235f, -1.5957691216f);  // -2u
        float h   = pre * __builtin_amdgcn_rcpf(1.0f + __expf(z));
        o0 = fmaf(h, w20[i], o0);
        o1 = fmaf(h, w21[i], o1);
    }

    float mu_x = fmaf(m, inv_gamma, -var_scale * o0);
    float lse  = fminf(fmaxf(o1, -10.0f), 10.0f);
    float sigma_x = fmaxf(var_scale * __expf(lse), 0.02f);
    if (tiny_t) { mu_x = 0.0f; sigma_x = 1.0f; }

    const float inv = 0.70710678118f * __builtin_amdgcn_rcpf(sigma_x);
    // boundary j (j=0..16) sits at j/8 - 1; erf argument a_j = fma(j, st, xb)
    const float xb = (-1.0f - mu_x) * inv;
    const float st = 0.125f * inv;

    if (full) {
        // In-wave shuffle transpose: 4 independent iterations; lane l handles
        // bins q*4..q*4+3 (q = l&3) of element 16s + (l>>2). Store address =
        // base + 16B*l per iteration -> perfectly coalesced, no LDS, no barrier.
        const int   q   = lane & 3;
        const float fj0 = (float)(q * 4);
        const size_t ebase = (size_t)b * D + d0 + (tid & ~63);  // wave's first element
#pragma unroll
        for (int s = 0; s < 4; ++s) {
            int   el  = s * 16 + (lane >> 2);
            float xbe = __shfl(xb, el, 64);
            float ste = __shfl(st, el, 64);
            float c0 = (q == 0) ? 0.0f : phi_fast(fmaf(fj0,        ste, xbe));
            float c1v =                  phi_fast(fmaf(fj0 + 1.0f, ste, xbe));
            float c2 =                   phi_fast(fmaf(fj0 + 2.0f, ste, xbe));
            float c3 =                   phi_fast(fmaf(fj0 + 3.0f, ste, xbe));
            float c4 = (q == 3) ? 1.0f : phi_fast(fmaf(fj0 + 4.0f, ste, xbe));
            f32x4 r;
            r.x = c1v - c0; r.y = c2 - c1v; r.z = c3 - c2; r.w = c4 - c3;
            __builtin_nontemporal_store(r, (f32x4*)out + (ebase + el) * 4 + q);
        }
    } else if (d < D) {
        // tail fallback (never taken for D % 256 == 0): direct stores
        float cdf[KBINS + 1];
        cdf[0] = 0.0f; cdf[KBINS] = 1.0f;
#pragma unroll
        for (int j = 1; j < KBINS; ++j)
            cdf[j] = phi_fast(fmaf((float)j, st, xb));
        float4* op = (float4*)(out + ((size_t)b * D + d) * (size_t)KBINS);
#pragma unroll
        for (int s = 0; s < 4; ++s)
            op[s] = make_float4(cdf[4*s+1] - cdf[4*s],   cdf[4*s+2] - cdf[4*s+1],
                                 cdf[4*s+3] - cdf[4*s+2], cdf[4*s+4] - cdf[4*s+3]);
    }
}

extern "C" void kernel_launch(void* const* d_in, const int* in_sizes, int n_in,
                              void* d_out, int out_size, void* d_ws, size_t ws_size,
                              hipStream_t stream) {
    const float* mu = (const float*)d_in[0];
    const float* t  = (const float*)d_in[1];
    const float* W1 = (const float*)d_in[2];
    const float* b1 = (const float*)d_in[3];
    const float* W2 = (const float*)d_in[4];
    const float* b2 = (const float*)d_in[5];
    float* out = (float*)d_out;

    const int B = in_sizes[1];          // t is [B,1]
    const int D = in_sizes[0] / B;      // mu is [B,D]

    dim3 block(256);
    dim3 grid((D + 255) / 256, B);
    bfn_kernel<<<grid, block, 0, stream>>>(mu, t, W1, b1, W2, b2, out, D);
}